// Round 2
// baseline (2789.653 us; speedup 1.0000x reference)
//
#include <hip/hip_runtime.h>
#include <stdint.h>

#define N_BOX 8400
#define NCLS 80
#define PSTRIDE 85
#define NW 132            // 64-bit words covering 8400
#define CONF_T 0.01f
#define NMS_T 0.2f
#define PD 12             // scan prefetch pipeline depth

typedef unsigned long long u64;

// ws layout (bytes)
#define OFF_DET     0                    // 8400 x 8 f32   = 268800
#define OFF_BOXES   268800               // 8400 float4    = 134400
#define OFF_KEYS    403200               // 8400 u64       = 67200
#define OFF_SIDX    470400               // 8400 int       = 33600
#define OFF_DETS    504000               // 8400 x 8 f32   = 268800
#define OFF_BOXESS  772800               // 8400 float4    = 134400
#define OFF_MASK    907200               // 8400 x 132 u64 = 8870400 (16B aligned)
#define OFF_KEEPW   9777600              // 132 u64        = 1056
#define OFF_VCNT    9778656              // 1 int

__device__ __forceinline__ unsigned fmap_desc(float f) {
    unsigned u = __float_as_uint(f);
    unsigned m = (u & 0x80000000u) ? ~u : (u | 0x80000000u); // monotone ascending
    return ~m;                                               // descending
}

// ---- kernel A: per-row preprocess ----
__global__ __launch_bounds__(256) void prep_k(const float* __restrict__ pred,
                                              float* __restrict__ det,
                                              float4* __restrict__ boxes,
                                              u64* __restrict__ keys,
                                              int* __restrict__ vcount) {
    int i = blockIdx.x * 256 + threadIdx.x;
    if (i >= N_BOX) return;
    const float* p = pred + (size_t)i * PSTRIDE;
    float cx = p[0], cy = p[1], w = p[2], h = p[3], obj = p[4];
    float hw = __fmul_rn(w, 0.5f), hh = __fmul_rn(h, 0.5f);
    float x1 = __fsub_rn(cx, hw), y1 = __fsub_rn(cy, hh);
    float x2 = __fadd_rn(cx, hw), y2 = __fadd_rn(cy, hh);
    float best = p[5];
    int arg = 0;
    for (int c = 1; c < NCLS; ++c) {
        float v = p[5 + c];
        if (v > best) { best = v; arg = c; }   // strict > keeps FIRST max (numpy argmax)
    }
    bool valid = (obj >= CONF_T);
    float score = valid ? obj : -1.0f;
    if (valid) atomicAdd(vcount, 1);
    keys[i] = ((u64)fmap_desc(score) << 32) | (unsigned)i;  // asc sort => score desc, idx asc (stable)
    float* d = det + (size_t)i * 8;
    d[0] = x1; d[1] = y1; d[2] = x2; d[3] = y2;
    d[4] = obj; d[5] = best; d[6] = (float)arg; d[7] = 0.0f;
    boxes[i] = make_float4(x1, y1, x2, y2);
}

// ---- kernel B: rank = #{keys < mine}; scatter index ----
__global__ __launch_bounds__(256) void rank_k(const u64* __restrict__ keys,
                                              int* __restrict__ sidx) {
    __shared__ u64 kl[4200];
    int i = blockIdx.x * 256 + threadIdx.x;
    bool act = (i < N_BOX);
    u64 my = act ? keys[i] : 0ull;
    int cnt = 0;
    for (int half = 0; half < 2; ++half) {
        int base = half * 4200;
        __syncthreads();
        for (int j = threadIdx.x; j < 4200; j += 256) kl[j] = keys[base + j];
        __syncthreads();
        if (act) {
            for (int j = 0; j < 4200; ++j) cnt += (kl[j] < my) ? 1 : 0;
        }
    }
    if (act) sidx[cnt] = i;   // keys distinct (index embedded) -> permutation
}

// ---- kernel C: gather sorted det/boxes ----
__global__ __launch_bounds__(256) void gather_k(const int* __restrict__ sidx,
                                                const float4* __restrict__ det,
                                                const float4* __restrict__ boxes,
                                                float4* __restrict__ det_s,
                                                float4* __restrict__ boxes_s) {
    int r = blockIdx.x * 256 + threadIdx.x;
    if (r >= N_BOX) return;
    int i = sidx[r];
    det_s[r * 2]     = det[i * 2];
    det_s[r * 2 + 1] = det[i * 2 + 1];
    boxes_s[r]       = boxes[i];
}

// ---- kernel D: suppression bitmask (upper triangle), torchvision-style ----
__global__ __launch_bounds__(64) void mask_k(const float4* __restrict__ boxes_s,
                                             u64* __restrict__ mask) {
    int cb = blockIdx.x, rb = blockIdx.y, t = threadIdx.x;
    int r = rb * 64 + t;
    if (cb < rb) {                       // lower triangle: zero-fill
        if (r < N_BOX) mask[(size_t)r * NW + cb] = 0ull;
        return;
    }
    __shared__ float4 cB[64];
    __shared__ float  cA[64];
    int c0 = cb * 64 + t;
    float4 b = (c0 < N_BOX) ? boxes_s[c0] : make_float4(0.f, 0.f, 0.f, 0.f);
    cB[t] = b;
    cA[t] = __fmul_rn(__fsub_rn(b.z, b.x), __fsub_rn(b.w, b.y));
    __syncthreads();
    if (r >= N_BOX) return;
    float4 rx = boxes_s[r];
    float ra = __fmul_rn(__fsub_rn(rx.z, rx.x), __fsub_rn(rx.w, rx.y));
    u64 bits = 0ull;
    int cbase = cb * 64;
    for (int j = 0; j < 64; ++j) {
        int c = cbase + j;
        if (c >= N_BOX || c <= r) continue;
        float4 cx4 = cB[j];
        float ltx = fmaxf(rx.x, cx4.x), lty = fmaxf(rx.y, cx4.y);
        float rbx = fminf(rx.z, cx4.z), rby = fminf(rx.w, cx4.w);
        float wx = fmaxf(__fsub_rn(rbx, ltx), 0.0f);
        float wy = fmaxf(__fsub_rn(rby, lty), 0.0f);
        float inter = __fmul_rn(wx, wy);
        float denom = __fadd_rn(__fsub_rn(__fadd_rn(ra, cA[j]), inter), 1e-9f);
        float iou = __fdiv_rn(inter, denom);
        if (iou > NMS_T) bits |= (1ull << j);
    }
    mask[(size_t)r * NW + cb] = bits;
}

// ---- kernel E: serial greedy scan, one wave, register remv + PD-deep prefetch ----
// lane l owns remv words 2l, 2l+1 (ra, rb) and 128+l for l<4 (rc).
__global__ __launch_bounds__(64) void scan_k(const u64* __restrict__ mask,
                                             const int* __restrict__ vcount,
                                             u64* __restrict__ keepw) {
    int lane = threadIdx.x;
    int V = *vcount;
    u64 ra = 0ull, rb = 0ull, rc = 0ull;
    u64 pa[PD], pb[PD], pc[PD], pq[PD];
    #pragma unroll
    for (int d = 0; d < PD; ++d) {
        if (d < V) {
            const u64* row = mask + (size_t)d * NW;
            ulonglong2 v = *(const ulonglong2*)(row + 2 * lane);
            pa[d] = v.x; pb[d] = v.y;
            pc[d] = (lane < 4) ? row[128 + lane] : 0ull;
            pq[d] = row[d >> 6];                 // broadcast: row's word (d>>6)
        }
    }
    u64 cur = 0ull;                              // remv word 0 starts empty
    for (int base = 0; base < V; base += PD) {
        #pragma unroll
        for (int d = 0; d < PD; ++d) {
            int j = base + d;
            if (j < V) {
                if ((j & 63) == 0 && j > 0) {    // word boundary: reload cur from owner lane
                    int w = j >> 6;
                    u64 rw = (w < 128) ? ((w & 1) ? rb : ra) : rc;
                    int src = (w < 128) ? (w >> 1) : (w - 128);
                    int lo = __shfl((int)(unsigned)rw, src);
                    int hi = __shfl((int)(unsigned)(rw >> 32), src);
                    cur = ((u64)(unsigned)hi << 32) | (unsigned)lo;
                }
                if (!((cur >> (j & 63)) & 1ull)) {   // alive (wave-uniform)
                    ra |= pa[d]; rb |= pb[d]; rc |= pc[d];
                    cur |= pq[d];
                }
                int jn = j + PD;
                if (jn < V) {                    // prefetch row jn into stage d
                    const u64* row = mask + (size_t)jn * NW;
                    ulonglong2 v = *(const ulonglong2*)(row + 2 * lane);
                    pa[d] = v.x; pb[d] = v.y;
                    pc[d] = (lane < 4) ? row[128 + lane] : 0ull;
                    pq[d] = row[jn >> 6];
                }
            }
        }
    }
    // keep = ~remv & validmask
    int w0 = 2 * lane, w1 = 2 * lane + 1, w2 = 128 + lane;
    u64 m0, m1, m2;
    {
        int b0 = w0 << 6;
        m0 = (b0 + 64 <= V) ? ~0ull : ((b0 >= V) ? 0ull : ((1ull << (V - b0)) - 1ull));
        int b1 = w1 << 6;
        m1 = (b1 + 64 <= V) ? ~0ull : ((b1 >= V) ? 0ull : ((1ull << (V - b1)) - 1ull));
        int b2 = w2 << 6;
        m2 = (b2 + 64 <= V) ? ~0ull : ((b2 >= V) ? 0ull : ((1ull << (V - b2)) - 1ull));
    }
    keepw[w0] = (~ra) & m0;
    keepw[w1] = (~rb) & m1;
    if (lane < 4) keepw[w2] = (~rc) & m2;
}

// ---- kernel F: masked write-out (7 cols) ----
__global__ __launch_bounds__(256) void out_k(const float* __restrict__ det_s,
                                             const u64* __restrict__ keepw,
                                             float* __restrict__ out) {
    int e = blockIdx.x * 256 + threadIdx.x;
    if (e >= N_BOX * 7) return;
    int r = e / 7, c = e - r * 7;
    bool k = (keepw[r >> 6] >> (r & 63)) & 1ull;
    out[e] = k ? det_s[r * 8 + c] : 0.0f;
}

extern "C" void kernel_launch(void* const* d_in, const int* in_sizes, int n_in,
                              void* d_out, int out_size, void* d_ws, size_t ws_size,
                              hipStream_t stream) {
    const float* pred = (const float*)d_in[0];
    char* ws = (char*)d_ws;
    float*  det     = (float*) (ws + OFF_DET);
    float4* boxes   = (float4*)(ws + OFF_BOXES);
    u64*    keys    = (u64*)   (ws + OFF_KEYS);
    int*    sidx    = (int*)   (ws + OFF_SIDX);
    float*  det_s   = (float*) (ws + OFF_DETS);
    float4* boxes_s = (float4*)(ws + OFF_BOXESS);
    u64*    mask    = (u64*)   (ws + OFF_MASK);
    u64*    keepw   = (u64*)   (ws + OFF_KEEPW);
    int*    vcount  = (int*)   (ws + OFF_VCNT);

    hipMemsetAsync(vcount, 0, 4, stream);
    prep_k  <<<(N_BOX + 255) / 256, 256, 0, stream>>>(pred, det, boxes, keys, vcount);
    rank_k  <<<(N_BOX + 255) / 256, 256, 0, stream>>>(keys, sidx);
    gather_k<<<(N_BOX + 255) / 256, 256, 0, stream>>>(sidx, (const float4*)det, boxes,
                                                      (float4*)det_s, boxes_s);
    mask_k  <<<dim3(NW, NW), 64, 0, stream>>>(boxes_s, mask);
    scan_k  <<<1, 64, 0, stream>>>(mask, vcount, keepw);
    out_k   <<<(N_BOX * 7 + 255) / 256, 256, 0, stream>>>(det_s, keepw, (float*)d_out);
}

// Round 3
// 2328.443 us; speedup vs baseline: 1.1981x; 1.1981x over previous
//
#include <hip/hip_runtime.h>
#include <stdint.h>

#define N_BOX 8400
#define NCLS 80
#define PSTRIDE 85
#define NW 132            // 64-bit words covering 8400
#define CONF_T 0.01f
#define NMS_T 0.2f
#define SPD 24            // scan pipeline depth (named registers, no arrays!)

typedef unsigned long long u64;

// ws layout (bytes)
#define OFF_DET     0                    // 8400 x 8 f32   = 268800
#define OFF_BOXES   268800               // 8400 float4    = 134400
#define OFF_KEYS    403200               // 8400 u64       = 67200
#define OFF_SIDX    470400               // 8400 int       = 33600
#define OFF_DETS    504000               // 8400 x 8 f32   = 268800
#define OFF_BOXESS  772800               // 8400 float4    = 134400
#define OFF_MASK    907200               // 8400 x 132 u64 = 8870400 (16B aligned)
#define OFF_KEEPW   9777600              // 132 u64        = 1056
#define OFF_VCNT    9778656              // 1 int

__device__ __forceinline__ unsigned fmap_desc(float f) {
    unsigned u = __float_as_uint(f);
    unsigned m = (u & 0x80000000u) ? ~u : (u | 0x80000000u); // monotone ascending
    return ~m;                                               // descending
}

__device__ __forceinline__ u64 readlane64(u64 v, int lane) {
    unsigned lo = (unsigned)__builtin_amdgcn_readlane((int)(unsigned)v, lane);
    unsigned hi = (unsigned)__builtin_amdgcn_readlane((int)(unsigned)(v >> 32), lane);
    return ((u64)hi << 32) | lo;
}

// ---- kernel A: per-row preprocess ----
__global__ __launch_bounds__(256) void prep_k(const float* __restrict__ pred,
                                              float* __restrict__ det,
                                              float4* __restrict__ boxes,
                                              u64* __restrict__ keys,
                                              int* __restrict__ vcount) {
    int i = blockIdx.x * 256 + threadIdx.x;
    if (i >= N_BOX) return;
    const float* p = pred + (size_t)i * PSTRIDE;
    float cx = p[0], cy = p[1], w = p[2], h = p[3], obj = p[4];
    float hw = __fmul_rn(w, 0.5f), hh = __fmul_rn(h, 0.5f);
    float x1 = __fsub_rn(cx, hw), y1 = __fsub_rn(cy, hh);
    float x2 = __fadd_rn(cx, hw), y2 = __fadd_rn(cy, hh);
    float best = p[5];
    int arg = 0;
    for (int c = 1; c < NCLS; ++c) {
        float v = p[5 + c];
        if (v > best) { best = v; arg = c; }   // strict > keeps FIRST max (numpy argmax)
    }
    bool valid = (obj >= CONF_T);
    float score = valid ? obj : -1.0f;
    if (valid) atomicAdd(vcount, 1);
    keys[i] = ((u64)fmap_desc(score) << 32) | (unsigned)i;  // asc sort => score desc, idx asc (stable)
    float* d = det + (size_t)i * 8;
    d[0] = x1; d[1] = y1; d[2] = x2; d[3] = y2;
    d[4] = obj; d[5] = best; d[6] = (float)arg; d[7] = 0.0f;
    boxes[i] = make_float4(x1, y1, x2, y2);
}

// ---- kernel B: rank = #{keys < mine}; scatter index ----
__global__ __launch_bounds__(256) void rank_k(const u64* __restrict__ keys,
                                              int* __restrict__ sidx) {
    __shared__ u64 kl[4200];
    int i = blockIdx.x * 256 + threadIdx.x;
    bool act = (i < N_BOX);
    u64 my = act ? keys[i] : 0ull;
    int cnt = 0;
    for (int half = 0; half < 2; ++half) {
        int base = half * 4200;
        __syncthreads();
        for (int j = threadIdx.x; j < 4200; j += 256) kl[j] = keys[base + j];
        __syncthreads();
        if (act) {
            for (int j = 0; j < 4200; ++j) cnt += (kl[j] < my) ? 1 : 0;
        }
    }
    if (act) sidx[cnt] = i;   // keys distinct (index embedded) -> permutation
}

// ---- kernel C: gather sorted det/boxes ----
__global__ __launch_bounds__(256) void gather_k(const int* __restrict__ sidx,
                                                const float4* __restrict__ det,
                                                const float4* __restrict__ boxes,
                                                float4* __restrict__ det_s,
                                                float4* __restrict__ boxes_s) {
    int r = blockIdx.x * 256 + threadIdx.x;
    if (r >= N_BOX) return;
    int i = sidx[r];
    det_s[r * 2]     = det[i * 2];
    det_s[r * 2 + 1] = det[i * 2 + 1];
    boxes_s[r]       = boxes[i];
}

// ---- kernel D: suppression bitmask (upper triangle), torchvision-style ----
__global__ __launch_bounds__(64) void mask_k(const float4* __restrict__ boxes_s,
                                             u64* __restrict__ mask) {
    int cb = blockIdx.x, rb = blockIdx.y, t = threadIdx.x;
    int r = rb * 64 + t;
    if (cb < rb) {                       // lower triangle: zero-fill
        if (r < N_BOX) mask[(size_t)r * NW + cb] = 0ull;
        return;
    }
    __shared__ float4 cB[64];
    __shared__ float  cA[64];
    int c0 = cb * 64 + t;
    float4 b = (c0 < N_BOX) ? boxes_s[c0] : make_float4(0.f, 0.f, 0.f, 0.f);
    cB[t] = b;
    cA[t] = __fmul_rn(__fsub_rn(b.z, b.x), __fsub_rn(b.w, b.y));
    __syncthreads();
    if (r >= N_BOX) return;
    float4 rx = boxes_s[r];
    float ra = __fmul_rn(__fsub_rn(rx.z, rx.x), __fsub_rn(rx.w, rx.y));
    u64 bits = 0ull;
    int cbase = cb * 64;
    for (int j = 0; j < 64; ++j) {
        int c = cbase + j;
        if (c >= N_BOX || c <= r) continue;
        float4 cx4 = cB[j];
        float ltx = fmaxf(rx.x, cx4.x), lty = fmaxf(rx.y, cx4.y);
        float rbx = fminf(rx.z, cx4.z), rby = fminf(rx.w, cx4.w);
        float wx = fmaxf(__fsub_rn(rbx, ltx), 0.0f);
        float wy = fmaxf(__fsub_rn(rby, lty), 0.0f);
        float inter = __fmul_rn(wx, wy);
        float denom = __fadd_rn(__fsub_rn(__fadd_rn(ra, cA[j]), inter), 1e-9f);
        float iou = __fdiv_rn(inter, denom);
        if (iou > NMS_T) bits |= (1ull << j);
    }
    mask[(size_t)r * NW + cb] = bits;
}

// ---- kernel E: serial greedy scan, one wave ----
// remv bitset in registers: lane l owns words 2l (Ra), 2l+1 (Rb); lanes 0..3 own 128+l (Rc).
// SPD-deep software pipeline in NAMED registers (rule #20: no runtime-indexed arrays).
// Per row j, 2 loads: dwordx4 (words 2l,2l+1) + merged load (lanes<4: tail word 128+l;
// lanes>=4: broadcast word j>>6, consumed via readlane from lane 4).
// cur (current remv word) kept wave-uniform; dead-box path is pure scalar test+branch.
__global__ __launch_bounds__(64) void scan_k(const u64* __restrict__ mask,
                                             const int* __restrict__ vcount,
                                             u64* __restrict__ keepw) {
    int lane = threadIdx.x;
    int V = *vcount;
    u64 Ra = 0ull, Rb = 0ull, Rc = 0ull;
    u64 cur = 0ull;

    u64 pa0,pb0,pc0, pa1,pb1,pc1, pa2,pb2,pc2, pa3,pb3,pc3;
    u64 pa4,pb4,pc4, pa5,pb5,pc5, pa6,pb6,pc6, pa7,pb7,pc7;
    u64 pa8,pb8,pc8, pa9,pb9,pc9, pa10,pb10,pc10, pa11,pb11,pc11;
    u64 pa12,pb12,pc12, pa13,pb13,pc13, pa14,pb14,pc14, pa15,pb15,pc15;
    u64 pa16,pb16,pc16, pa17,pb17,pc17, pa18,pb18,pc18, pa19,pb19,pc19;
    u64 pa20,pb20,pc20, pa21,pb21,pc21, pa22,pb22,pc22, pa23,pb23,pc23;

#define LOADST(s, ridx) do {                                            \
        const u64* row_ = mask + (size_t)(ridx) * NW;                   \
        ulonglong2 v2_ = *(const ulonglong2*)(row_ + 2 * lane);         \
        pa##s = v2_.x; pb##s = v2_.y;                                   \
        int widx_ = (lane < 4) ? (128 + lane) : ((ridx) >> 6);          \
        pc##s = row_[widx_];                                            \
    } while (0)

#define STEP(s, jj) do {                                                \
        int j_ = (jj);                                                  \
        if (j_ < V) {                                                   \
            if ((j_ & 63) == 0 && j_ > 0) {                             \
                int w_ = j_ >> 6;                                       \
                u64 rw_ = (w_ < 128) ? ((w_ & 1) ? Rb : Ra) : Rc;       \
                int sl_ = (w_ < 128) ? (w_ >> 1) : (w_ - 128);          \
                cur = readlane64(rw_, sl_);                             \
            }                                                           \
            if (!((cur >> (j_ & 63)) & 1ull)) {                         \
                Ra |= pa##s; Rb |= pb##s; Rc |= pc##s;                  \
                cur |= readlane64(pc##s, 4);                            \
            }                                                           \
            int jn_ = j_ + SPD;                                         \
            if (jn_ < V) LOADST(s, jn_);                                \
        }                                                               \
    } while (0)

    // prologue: fill all SPD stages
    if (V >  0) LOADST(0, 0);   if (V >  1) LOADST(1, 1);
    if (V >  2) LOADST(2, 2);   if (V >  3) LOADST(3, 3);
    if (V >  4) LOADST(4, 4);   if (V >  5) LOADST(5, 5);
    if (V >  6) LOADST(6, 6);   if (V >  7) LOADST(7, 7);
    if (V >  8) LOADST(8, 8);   if (V >  9) LOADST(9, 9);
    if (V > 10) LOADST(10, 10); if (V > 11) LOADST(11, 11);
    if (V > 12) LOADST(12, 12); if (V > 13) LOADST(13, 13);
    if (V > 14) LOADST(14, 14); if (V > 15) LOADST(15, 15);
    if (V > 16) LOADST(16, 16); if (V > 17) LOADST(17, 17);
    if (V > 18) LOADST(18, 18); if (V > 19) LOADST(19, 19);
    if (V > 20) LOADST(20, 20); if (V > 21) LOADST(21, 21);
    if (V > 22) LOADST(22, 22); if (V > 23) LOADST(23, 23);

    for (int base = 0; base < V; base += SPD) {
        STEP(0,  base + 0);  STEP(1,  base + 1);  STEP(2,  base + 2);
        STEP(3,  base + 3);  STEP(4,  base + 4);  STEP(5,  base + 5);
        STEP(6,  base + 6);  STEP(7,  base + 7);  STEP(8,  base + 8);
        STEP(9,  base + 9);  STEP(10, base + 10); STEP(11, base + 11);
        STEP(12, base + 12); STEP(13, base + 13); STEP(14, base + 14);
        STEP(15, base + 15); STEP(16, base + 16); STEP(17, base + 17);
        STEP(18, base + 18); STEP(19, base + 19); STEP(20, base + 20);
        STEP(21, base + 21); STEP(22, base + 22); STEP(23, base + 23);
    }

    // keep = ~remv & validmask
    int w0 = 2 * lane, w1 = 2 * lane + 1, w2 = 128 + lane;
    int b0 = w0 << 6, b1 = w1 << 6, b2 = w2 << 6;
    u64 m0 = (b0 + 64 <= V) ? ~0ull : ((b0 >= V) ? 0ull : ((1ull << (V - b0)) - 1ull));
    u64 m1 = (b1 + 64 <= V) ? ~0ull : ((b1 >= V) ? 0ull : ((1ull << (V - b1)) - 1ull));
    u64 m2 = (b2 + 64 <= V) ? ~0ull : ((b2 >= V) ? 0ull : ((1ull << (V - b2)) - 1ull));
    keepw[w0] = (~Ra) & m0;
    keepw[w1] = (~Rb) & m1;
    if (lane < 4) keepw[w2] = (~Rc) & m2;
}

// ---- kernel F: masked write-out (7 cols) ----
__global__ __launch_bounds__(256) void out_k(const float* __restrict__ det_s,
                                             const u64* __restrict__ keepw,
                                             float* __restrict__ out) {
    int e = blockIdx.x * 256 + threadIdx.x;
    if (e >= N_BOX * 7) return;
    int r = e / 7, c = e - r * 7;
    bool k = (keepw[r >> 6] >> (r & 63)) & 1ull;
    out[e] = k ? det_s[r * 8 + c] : 0.0f;
}

extern "C" void kernel_launch(void* const* d_in, const int* in_sizes, int n_in,
                              void* d_out, int out_size, void* d_ws, size_t ws_size,
                              hipStream_t stream) {
    const float* pred = (const float*)d_in[0];
    char* ws = (char*)d_ws;
    float*  det     = (float*) (ws + OFF_DET);
    float4* boxes   = (float4*)(ws + OFF_BOXES);
    u64*    keys    = (u64*)   (ws + OFF_KEYS);
    int*    sidx    = (int*)   (ws + OFF_SIDX);
    float*  det_s   = (float*) (ws + OFF_DETS);
    float4* boxes_s = (float4*)(ws + OFF_BOXESS);
    u64*    mask    = (u64*)   (ws + OFF_MASK);
    u64*    keepw   = (u64*)   (ws + OFF_KEEPW);
    int*    vcount  = (int*)   (ws + OFF_VCNT);

    hipMemsetAsync(vcount, 0, 4, stream);
    prep_k  <<<(N_BOX + 255) / 256, 256, 0, stream>>>(pred, det, boxes, keys, vcount);
    rank_k  <<<(N_BOX + 255) / 256, 256, 0, stream>>>(keys, sidx);
    gather_k<<<(N_BOX + 255) / 256, 256, 0, stream>>>(sidx, (const float4*)det, boxes,
                                                      (float4*)det_s, boxes_s);
    mask_k  <<<dim3(NW, NW), 64, 0, stream>>>(boxes_s, mask);
    scan_k  <<<1, 64, 0, stream>>>(mask, vcount, keepw);
    out_k   <<<(N_BOX * 7 + 255) / 256, 256, 0, stream>>>(det_s, keepw, (float*)d_out);
}

// Round 4
// 651.479 us; speedup vs baseline: 4.2820x; 3.5741x over previous
//
#include <hip/hip_runtime.h>
#include <stdint.h>

#define N_BOX 8400
#define NCLS 80
#define PSTRIDE 85
#define NW 132            // 64-bit words covering 8400
#define CONF_T 0.01f
#define NMS_T 0.2f
#define SPD 32            // scan pipeline depth (named registers, unconditional loads)

typedef unsigned long long u64;

// ws layout (bytes)
#define OFF_DET     0                    // 8400 x 8 f32   = 268800
#define OFF_BOXES   268800               // 8400 float4    = 134400
#define OFF_KEYS    403200               // 8400 u64       = 67200
#define OFF_SIDX    470400               // 8400 int       = 33600
#define OFF_DETS    504000               // 8400 x 8 f32   = 268800
#define OFF_BOXESS  772800               // 8400 float4    = 134400
#define OFF_MASK    907200               // 8400 x 132 u64 = 8870400 (16B aligned)
#define OFF_KEEPW   9777600              // 132 u64        = 1056
#define OFF_VCNT    9778656              // 1 int

__device__ __forceinline__ unsigned fmap_desc(float f) {
    unsigned u = __float_as_uint(f);
    unsigned m = (u & 0x80000000u) ? ~u : (u | 0x80000000u); // monotone ascending
    return ~m;                                               // descending
}

__device__ __forceinline__ u64 readlane64(u64 v, int lane) {
    unsigned lo = (unsigned)__builtin_amdgcn_readlane((int)(unsigned)v, lane);
    unsigned hi = (unsigned)__builtin_amdgcn_readlane((int)(unsigned)(v >> 32), lane);
    return ((u64)hi << 32) | lo;
}

// ---- kernel A: per-row preprocess ----
__global__ __launch_bounds__(256) void prep_k(const float* __restrict__ pred,
                                              float* __restrict__ det,
                                              float4* __restrict__ boxes,
                                              u64* __restrict__ keys,
                                              int* __restrict__ vcount) {
    int i = blockIdx.x * 256 + threadIdx.x;
    if (i >= N_BOX) return;
    const float* p = pred + (size_t)i * PSTRIDE;
    float cx = p[0], cy = p[1], w = p[2], h = p[3], obj = p[4];
    float hw = __fmul_rn(w, 0.5f), hh = __fmul_rn(h, 0.5f);
    float x1 = __fsub_rn(cx, hw), y1 = __fsub_rn(cy, hh);
    float x2 = __fadd_rn(cx, hw), y2 = __fadd_rn(cy, hh);
    float best = p[5];
    int arg = 0;
    for (int c = 1; c < NCLS; ++c) {
        float v = p[5 + c];
        if (v > best) { best = v; arg = c; }   // strict > keeps FIRST max (numpy argmax)
    }
    bool valid = (obj >= CONF_T);
    float score = valid ? obj : -1.0f;
    if (valid) atomicAdd(vcount, 1);
    keys[i] = ((u64)fmap_desc(score) << 32) | (unsigned)i;  // asc sort => score desc, idx asc (stable)
    float* d = det + (size_t)i * 8;
    d[0] = x1; d[1] = y1; d[2] = x2; d[3] = y2;
    d[4] = obj; d[5] = best; d[6] = (float)arg; d[7] = 0.0f;
    boxes[i] = make_float4(x1, y1, x2, y2);
}

// ---- kernel B: rank = #{keys < mine}; scatter index ----
__global__ __launch_bounds__(256) void rank_k(const u64* __restrict__ keys,
                                              int* __restrict__ sidx) {
    __shared__ u64 kl[4200];
    int i = blockIdx.x * 256 + threadIdx.x;
    bool act = (i < N_BOX);
    u64 my = act ? keys[i] : 0ull;
    int cnt = 0;
    for (int half = 0; half < 2; ++half) {
        int base = half * 4200;
        __syncthreads();
        for (int j = threadIdx.x; j < 4200; j += 256) kl[j] = keys[base + j];
        __syncthreads();
        if (act) {
            for (int j = 0; j < 4200; ++j) cnt += (kl[j] < my) ? 1 : 0;
        }
    }
    if (act) sidx[cnt] = i;   // keys distinct (index embedded) -> permutation
}

// ---- kernel C: gather sorted det/boxes ----
__global__ __launch_bounds__(256) void gather_k(const int* __restrict__ sidx,
                                                const float4* __restrict__ det,
                                                const float4* __restrict__ boxes,
                                                float4* __restrict__ det_s,
                                                float4* __restrict__ boxes_s) {
    int r = blockIdx.x * 256 + threadIdx.x;
    if (r >= N_BOX) return;
    int i = sidx[r];
    det_s[r * 2]     = det[i * 2];
    det_s[r * 2 + 1] = det[i * 2 + 1];
    boxes_s[r]       = boxes[i];
}

// ---- kernel D: suppression bitmask (upper triangle), torchvision-style ----
__global__ __launch_bounds__(64) void mask_k(const float4* __restrict__ boxes_s,
                                             u64* __restrict__ mask) {
    int cb = blockIdx.x, rb = blockIdx.y, t = threadIdx.x;
    int r = rb * 64 + t;
    if (cb < rb) {                       // lower triangle: zero-fill
        if (r < N_BOX) mask[(size_t)r * NW + cb] = 0ull;
        return;
    }
    __shared__ float4 cB[64];
    __shared__ float  cA[64];
    int c0 = cb * 64 + t;
    float4 b = (c0 < N_BOX) ? boxes_s[c0] : make_float4(0.f, 0.f, 0.f, 0.f);
    cB[t] = b;
    cA[t] = __fmul_rn(__fsub_rn(b.z, b.x), __fsub_rn(b.w, b.y));
    __syncthreads();
    if (r >= N_BOX) return;
    float4 rx = boxes_s[r];
    float ra = __fmul_rn(__fsub_rn(rx.z, rx.x), __fsub_rn(rx.w, rx.y));
    u64 bits = 0ull;
    int cbase = cb * 64;
    for (int j = 0; j < 64; ++j) {
        int c = cbase + j;
        if (c >= N_BOX || c <= r) continue;
        float4 cx4 = cB[j];
        float ltx = fmaxf(rx.x, cx4.x), lty = fmaxf(rx.y, cx4.y);
        float rbx = fminf(rx.z, cx4.z), rby = fminf(rx.w, cx4.w);
        float wx = fmaxf(__fsub_rn(rbx, ltx), 0.0f);
        float wy = fmaxf(__fsub_rn(rby, lty), 0.0f);
        float inter = __fmul_rn(wx, wy);
        float denom = __fadd_rn(__fsub_rn(__fadd_rn(ra, cA[j]), inter), 1e-9f);
        float iou = __fdiv_rn(inter, denom);
        if (iou > NMS_T) bits |= (1ull << j);
    }
    mask[(size_t)r * NW + cb] = bits;
}

// ---- kernel E: serial greedy scan, one wave ----
// remv bitset in registers: lane l owns words 2l (Ra), 2l+1 (Rb); lanes 0..3 own 128+l (Rc).
// SPD-deep software pipeline in NAMED registers. ALL loads are UNCONDITIONAL
// (row index clamped to V-1; duplicates harmless since OR is idempotent and
// out-of-range steps never consume) so outstanding-load counts are static and
// the compiler can emit counted s_waitcnt vmcnt(N) instead of draining.
__global__ __launch_bounds__(64) void scan_k(const u64* __restrict__ mask,
                                             const int* __restrict__ vcount,
                                             u64* __restrict__ keepw) {
    int lane = threadIdx.x;
    int V = *vcount;
    u64 Ra = 0ull, Rb = 0ull, Rc = 0ull;
    u64 cur = 0ull;

    if (V > 0) {
        u64 pa0,pb0,pc0, pa1,pb1,pc1, pa2,pb2,pc2, pa3,pb3,pc3;
        u64 pa4,pb4,pc4, pa5,pb5,pc5, pa6,pb6,pc6, pa7,pb7,pc7;
        u64 pa8,pb8,pc8, pa9,pb9,pc9, pa10,pb10,pc10, pa11,pb11,pc11;
        u64 pa12,pb12,pc12, pa13,pb13,pc13, pa14,pb14,pc14, pa15,pb15,pc15;
        u64 pa16,pb16,pc16, pa17,pb17,pc17, pa18,pb18,pc18, pa19,pb19,pc19;
        u64 pa20,pb20,pc20, pa21,pb21,pc21, pa22,pb22,pc22, pa23,pb23,pc23;
        u64 pa24,pb24,pc24, pa25,pb25,pc25, pa26,pb26,pc26, pa27,pb27,pc27;
        u64 pa28,pb28,pc28, pa29,pb29,pc29, pa30,pb30,pc30, pa31,pb31,pc31;

#define LOADST(s, ridx) do {                                            \
        const u64* row_ = mask + (size_t)(ridx) * NW;                   \
        ulonglong2 v2_ = *(const ulonglong2*)(row_ + 2 * lane);         \
        pa##s = v2_.x; pb##s = v2_.y;                                   \
        int widx_ = (lane < 4) ? (128 + lane) : ((ridx) >> 6);          \
        pc##s = row_[widx_];                                            \
    } while (0)

#define PRO(s) do { int r_ = ((s) < V) ? (s) : (V - 1); LOADST(s, r_); } while (0)

#define STEP(s, jj) do {                                                \
        int j_ = (jj);                                                  \
        if (j_ < V) {                                                   \
            if ((j_ & 63) == 0 && j_ > 0) {                             \
                int w_ = j_ >> 6;                                       \
                u64 rw_ = (w_ < 128) ? ((w_ & 1) ? Rb : Ra) : Rc;       \
                int sl_ = (w_ < 128) ? (w_ >> 1) : (w_ - 128);          \
                cur = readlane64(rw_, sl_);                             \
            }                                                           \
            if (!((cur >> (j_ & 63)) & 1ull)) {                         \
                Ra |= pa##s; Rb |= pb##s; Rc |= pc##s;                  \
                cur |= readlane64(pc##s, 4);                            \
            }                                                           \
        }                                                               \
        int jn_ = j_ + SPD;                                             \
        jn_ = (jn_ < V) ? jn_ : (V - 1);                                \
        LOADST(s, jn_);                                                 \
    } while (0)

        // prologue: fill all SPD stages (unconditional, clamped)
        PRO(0);  PRO(1);  PRO(2);  PRO(3);  PRO(4);  PRO(5);  PRO(6);  PRO(7);
        PRO(8);  PRO(9);  PRO(10); PRO(11); PRO(12); PRO(13); PRO(14); PRO(15);
        PRO(16); PRO(17); PRO(18); PRO(19); PRO(20); PRO(21); PRO(22); PRO(23);
        PRO(24); PRO(25); PRO(26); PRO(27); PRO(28); PRO(29); PRO(30); PRO(31);

        for (int base = 0; base < V; base += SPD) {
            STEP(0,  base + 0);  STEP(1,  base + 1);  STEP(2,  base + 2);
            STEP(3,  base + 3);  STEP(4,  base + 4);  STEP(5,  base + 5);
            STEP(6,  base + 6);  STEP(7,  base + 7);  STEP(8,  base + 8);
            STEP(9,  base + 9);  STEP(10, base + 10); STEP(11, base + 11);
            STEP(12, base + 12); STEP(13, base + 13); STEP(14, base + 14);
            STEP(15, base + 15); STEP(16, base + 16); STEP(17, base + 17);
            STEP(18, base + 18); STEP(19, base + 19); STEP(20, base + 20);
            STEP(21, base + 21); STEP(22, base + 22); STEP(23, base + 23);
            STEP(24, base + 24); STEP(25, base + 25); STEP(26, base + 26);
            STEP(27, base + 27); STEP(28, base + 28); STEP(29, base + 29);
            STEP(30, base + 30); STEP(31, base + 31);
        }
    }

    // keep = ~remv & validmask
    int w0 = 2 * lane, w1 = 2 * lane + 1, w2 = 128 + lane;
    int b0 = w0 << 6, b1 = w1 << 6, b2 = w2 << 6;
    u64 m0 = (b0 + 64 <= V) ? ~0ull : ((b0 >= V) ? 0ull : ((1ull << (V - b0)) - 1ull));
    u64 m1 = (b1 + 64 <= V) ? ~0ull : ((b1 >= V) ? 0ull : ((1ull << (V - b1)) - 1ull));
    u64 m2 = (b2 + 64 <= V) ? ~0ull : ((b2 >= V) ? 0ull : ((1ull << (V - b2)) - 1ull));
    keepw[w0] = (~Ra) & m0;
    keepw[w1] = (~Rb) & m1;
    if (lane < 4) keepw[w2] = (~Rc) & m2;
}

// ---- kernel F: masked write-out (7 cols) ----
__global__ __launch_bounds__(256) void out_k(const float* __restrict__ det_s,
                                             const u64* __restrict__ keepw,
                                             float* __restrict__ out) {
    int e = blockIdx.x * 256 + threadIdx.x;
    if (e >= N_BOX * 7) return;
    int r = e / 7, c = e - r * 7;
    bool k = (keepw[r >> 6] >> (r & 63)) & 1ull;
    out[e] = k ? det_s[r * 8 + c] : 0.0f;
}

extern "C" void kernel_launch(void* const* d_in, const int* in_sizes, int n_in,
                              void* d_out, int out_size, void* d_ws, size_t ws_size,
                              hipStream_t stream) {
    const float* pred = (const float*)d_in[0];
    char* ws = (char*)d_ws;
    float*  det     = (float*) (ws + OFF_DET);
    float4* boxes   = (float4*)(ws + OFF_BOXES);
    u64*    keys    = (u64*)   (ws + OFF_KEYS);
    int*    sidx    = (int*)   (ws + OFF_SIDX);
    float*  det_s   = (float*) (ws + OFF_DETS);
    float4* boxes_s = (float4*)(ws + OFF_BOXESS);
    u64*    mask    = (u64*)   (ws + OFF_MASK);
    u64*    keepw   = (u64*)   (ws + OFF_KEEPW);
    int*    vcount  = (int*)   (ws + OFF_VCNT);

    hipMemsetAsync(vcount, 0, 4, stream);
    prep_k  <<<(N_BOX + 255) / 256, 256, 0, stream>>>(pred, det, boxes, keys, vcount);
    rank_k  <<<(N_BOX + 255) / 256, 256, 0, stream>>>(keys, sidx);
    gather_k<<<(N_BOX + 255) / 256, 256, 0, stream>>>(sidx, (const float4*)det, boxes,
                                                      (float4*)det_s, boxes_s);
    mask_k  <<<dim3(NW, NW), 64, 0, stream>>>(boxes_s, mask);
    scan_k  <<<1, 64, 0, stream>>>(mask, vcount, keepw);
    out_k   <<<(N_BOX * 7 + 255) / 256, 256, 0, stream>>>(det_s, keepw, (float*)d_out);
}

// Round 5
// 258.714 us; speedup vs baseline: 10.7828x; 2.5181x over previous
//
#include <hip/hip_runtime.h>
#include <stdint.h>

#define N_BOX 8400
#define NCLS 80
#define PSTRIDE 85
#define NW 132            // 64-bit words covering 8400
#define CONF_T 0.01f
#define NMS_T 0.2f

typedef unsigned long long u64;

// ws layout (bytes)
#define OFF_DET     0                    // 8400 x 8 f32   = 268800
#define OFF_BOXES   268800               // 8400 float4    = 134400
#define OFF_KEYS    403200               // 8400 u64       = 67200
#define OFF_SIDX    470400               // 8400 int       = 33600
#define OFF_DETS    504000               // 8400 x 8 f32   = 268800
#define OFF_BOXESS  772800               // 8400 float4    = 134400
#define OFF_MASK    907200               // 8400 x 132 u64 = 8870400 (16B aligned)
#define OFF_KEEPW   9777600              // 132 u64        = 1056
#define OFF_VCNT    9778656              // 1 int

__device__ __forceinline__ unsigned fmap_desc(float f) {
    unsigned u = __float_as_uint(f);
    unsigned m = (u & 0x80000000u) ? ~u : (u | 0x80000000u); // monotone ascending
    return ~m;                                               // descending
}

__device__ __forceinline__ u64 readlane64(u64 v, int lane) {
    unsigned lo = (unsigned)__builtin_amdgcn_readlane((int)(unsigned)v, lane);
    unsigned hi = (unsigned)__builtin_amdgcn_readlane((int)(unsigned)(v >> 32), lane);
    return ((u64)hi << 32) | lo;
}

// ---- kernel A: per-row preprocess ----
__global__ __launch_bounds__(256) void prep_k(const float* __restrict__ pred,
                                              float* __restrict__ det,
                                              float4* __restrict__ boxes,
                                              u64* __restrict__ keys,
                                              int* __restrict__ vcount) {
    int i = blockIdx.x * 256 + threadIdx.x;
    if (i >= N_BOX) return;
    const float* p = pred + (size_t)i * PSTRIDE;
    float cx = p[0], cy = p[1], w = p[2], h = p[3], obj = p[4];
    float hw = __fmul_rn(w, 0.5f), hh = __fmul_rn(h, 0.5f);
    float x1 = __fsub_rn(cx, hw), y1 = __fsub_rn(cy, hh);
    float x2 = __fadd_rn(cx, hw), y2 = __fadd_rn(cy, hh);
    float best = p[5];
    int arg = 0;
    for (int c = 1; c < NCLS; ++c) {
        float v = p[5 + c];
        if (v > best) { best = v; arg = c; }   // strict > keeps FIRST max (numpy argmax)
    }
    bool valid = (obj >= CONF_T);
    float score = valid ? obj : -1.0f;
    if (valid) atomicAdd(vcount, 1);
    keys[i] = ((u64)fmap_desc(score) << 32) | (unsigned)i;  // asc sort => score desc, idx asc (stable)
    float* d = det + (size_t)i * 8;
    d[0] = x1; d[1] = y1; d[2] = x2; d[3] = y2;
    d[4] = obj; d[5] = best; d[6] = (float)arg; d[7] = 0.0f;
    boxes[i] = make_float4(x1, y1, x2, y2);
}

// ---- kernel B: rank = #{keys < mine}; scatter index ----
__global__ __launch_bounds__(256) void rank_k(const u64* __restrict__ keys,
                                              int* __restrict__ sidx) {
    __shared__ u64 kl[4200];
    int i = blockIdx.x * 256 + threadIdx.x;
    bool act = (i < N_BOX);
    u64 my = act ? keys[i] : 0ull;
    int cnt = 0;
    for (int half = 0; half < 2; ++half) {
        int base = half * 4200;
        __syncthreads();
        for (int j = threadIdx.x; j < 4200; j += 256) kl[j] = keys[base + j];
        __syncthreads();
        if (act) {
            for (int j = 0; j < 4200; ++j) cnt += (kl[j] < my) ? 1 : 0;
        }
    }
    if (act) sidx[cnt] = i;   // keys distinct (index embedded) -> permutation
}

// ---- kernel C: gather sorted det/boxes ----
__global__ __launch_bounds__(256) void gather_k(const int* __restrict__ sidx,
                                                const float4* __restrict__ det,
                                                const float4* __restrict__ boxes,
                                                float4* __restrict__ det_s,
                                                float4* __restrict__ boxes_s) {
    int r = blockIdx.x * 256 + threadIdx.x;
    if (r >= N_BOX) return;
    int i = sidx[r];
    det_s[r * 2]     = det[i * 2];
    det_s[r * 2 + 1] = det[i * 2 + 1];
    boxes_s[r]       = boxes[i];
}

// ---- kernel D: suppression bitmask (upper triangle), torchvision-style ----
__global__ __launch_bounds__(64) void mask_k(const float4* __restrict__ boxes_s,
                                             u64* __restrict__ mask) {
    int cb = blockIdx.x, rb = blockIdx.y, t = threadIdx.x;
    int r = rb * 64 + t;
    if (cb < rb) {                       // lower triangle: zero-fill
        if (r < N_BOX) mask[(size_t)r * NW + cb] = 0ull;
        return;
    }
    __shared__ float4 cB[64];
    __shared__ float  cA[64];
    int c0 = cb * 64 + t;
    float4 b = (c0 < N_BOX) ? boxes_s[c0] : make_float4(0.f, 0.f, 0.f, 0.f);
    cB[t] = b;
    cA[t] = __fmul_rn(__fsub_rn(b.z, b.x), __fsub_rn(b.w, b.y));
    __syncthreads();
    if (r >= N_BOX) return;
    float4 rx = boxes_s[r];
    float ra = __fmul_rn(__fsub_rn(rx.z, rx.x), __fsub_rn(rx.w, rx.y));
    u64 bits = 0ull;
    int cbase = cb * 64;
    for (int j = 0; j < 64; ++j) {
        int c = cbase + j;
        if (c >= N_BOX || c <= r) continue;
        float4 cx4 = cB[j];
        float ltx = fmaxf(rx.x, cx4.x), lty = fmaxf(rx.y, cx4.y);
        float rbx = fminf(rx.z, cx4.z), rby = fminf(rx.w, cx4.w);
        float wx = fmaxf(__fsub_rn(rbx, ltx), 0.0f);
        float wy = fmaxf(__fsub_rn(rby, lty), 0.0f);
        float inter = __fmul_rn(wx, wy);
        float denom = __fadd_rn(__fsub_rn(__fadd_rn(ra, cA[j]), inter), 1e-9f);
        float iou = __fdiv_rn(inter, denom);
        if (iou > NMS_T) bits |= (1ull << j);
    }
    mask[(size_t)r * NW + cb] = bits;
}

// ---- kernel E: block-wise greedy scan, one wave ----
// Per 64-box block w:
//   * diag tile: lane l holds mask[(64w+l)*NW + w] (ONE coalesced load, prefetched
//     8 blocks ahead in named regs d0..d7 — addresses are static).
//   * O(alive) in-register resolve: iterate only over surviving leaders via ctz.
//   * only ALIVE boxes OR their full 132-word row into lane-owned remv regs
//     (Ra=word 2l, Rb=word 2l+1, Rc=word 128+l for l<4), batched 4 rows/wait.
__global__ __launch_bounds__(64) void scan_k(const u64* __restrict__ mask,
                                             const int* __restrict__ vcount,
                                             u64* __restrict__ keepw) {
    int lane = threadIdx.x;
    int V = *vcount;
    u64 Ra = 0ull, Rb = 0ull, Rc = 0ull;
    u64 d0, d1, d2, d3, d4, d5, d6, d7;

#define LDIAG(dst, w) do {                                              \
        int wc_ = (w) < NW ? (w) : (NW - 1);                            \
        int r_  = wc_ * 64 + lane;                                      \
        r_ = r_ < N_BOX ? r_ : (N_BOX - 1);                             \
        dst = mask[(size_t)r_ * NW + wc_];                              \
    } while (0)

#define PROC(w_, dreg) do {                                             \
        if ((w_) < NW) {                                                \
            int base_ = (w_) * 64;                                      \
            if (base_ < V) {                                            \
                int nb_ = V - base_; nb_ = nb_ < 64 ? nb_ : 64;         \
                u64 msk_ = (nb_ == 64) ? ~0ull : ((1ull << nb_) - 1ull);\
                u64 rw_ = ((w_) < 128) ? (((w_) & 1) ? Rb : Ra) : Rc;   \
                int sl_ = ((w_) < 128) ? ((w_) >> 1) : ((w_) - 128);    \
                u64 cur_ = readlane64(rw_, sl_);                        \
                u64 notsup_ = (~cur_) & msk_;                           \
                while (notsup_) {          /* one iter per LEADER */    \
                    int b_ = __builtin_ctzll(notsup_);                  \
                    u64 rowb_ = readlane64(dreg, b_);                   \
                    cur_ |= rowb_;                                      \
                    notsup_ &= ~rowb_;                                  \
                    notsup_ &= notsup_ - 1ull;                          \
                }                                                       \
                u64 alive_ = (~cur_) & msk_;                            \
                if (lane == 0) keepw[w_] = alive_;                      \
                u64 rem_ = alive_;                                      \
                while (rem_) {             /* OR alive rows, 4/wait */  \
                    int b0_ = __builtin_ctzll(rem_); rem_ &= rem_ - 1;  \
                    int b1_ = rem_ ? __builtin_ctzll(rem_) : b0_;       \
                    if (rem_) rem_ &= rem_ - 1;                         \
                    int b2_ = rem_ ? __builtin_ctzll(rem_) : b0_;       \
                    if (rem_) rem_ &= rem_ - 1;                         \
                    int b3_ = rem_ ? __builtin_ctzll(rem_) : b0_;       \
                    if (rem_) rem_ &= rem_ - 1;                         \
                    const u64* r0_ = mask + (size_t)(base_ + b0_) * NW; \
                    const u64* r1_ = mask + (size_t)(base_ + b1_) * NW; \
                    const u64* r2_ = mask + (size_t)(base_ + b2_) * NW; \
                    const u64* r3_ = mask + (size_t)(base_ + b3_) * NW; \
                    ulonglong2 v0_ = *(const ulonglong2*)(r0_ + 2*lane);\
                    ulonglong2 v1_ = *(const ulonglong2*)(r1_ + 2*lane);\
                    ulonglong2 v2_ = *(const ulonglong2*)(r2_ + 2*lane);\
                    ulonglong2 v3_ = *(const ulonglong2*)(r3_ + 2*lane);\
                    int tw_ = (lane < 4) ? (128 + lane) : 131;          \
                    u64 t0_ = r0_[tw_], t1_ = r1_[tw_];                 \
                    u64 t2_ = r2_[tw_], t3_ = r3_[tw_];                 \
                    Ra |= v0_.x | v1_.x | v2_.x | v3_.x;                \
                    Rb |= v0_.y | v1_.y | v2_.y | v3_.y;                \
                    Rc |= t0_ | t1_ | t2_ | t3_;                        \
                }                                                       \
            } else {                                                    \
                if (lane == 0) keepw[w_] = 0ull;                        \
            }                                                           \
        }                                                               \
    } while (0)

    LDIAG(d0, 0); LDIAG(d1, 1); LDIAG(d2, 2); LDIAG(d3, 3);
    LDIAG(d4, 4); LDIAG(d5, 5); LDIAG(d6, 6); LDIAG(d7, 7);

    for (int w = 0; w < NW; w += 8) {
        PROC(w + 0, d0); LDIAG(d0, w + 8);
        PROC(w + 1, d1); LDIAG(d1, w + 9);
        PROC(w + 2, d2); LDIAG(d2, w + 10);
        PROC(w + 3, d3); LDIAG(d3, w + 11);
        PROC(w + 4, d4); LDIAG(d4, w + 12);
        PROC(w + 5, d5); LDIAG(d5, w + 13);
        PROC(w + 6, d6); LDIAG(d6, w + 14);
        PROC(w + 7, d7); LDIAG(d7, w + 15);
    }
#undef PROC
#undef LDIAG
}

// ---- kernel F: masked write-out (7 cols) ----
__global__ __launch_bounds__(256) void out_k(const float* __restrict__ det_s,
                                             const u64* __restrict__ keepw,
                                             float* __restrict__ out) {
    int e = blockIdx.x * 256 + threadIdx.x;
    if (e >= N_BOX * 7) return;
    int r = e / 7, c = e - r * 7;
    bool k = (keepw[r >> 6] >> (r & 63)) & 1ull;
    out[e] = k ? det_s[r * 8 + c] : 0.0f;
}

extern "C" void kernel_launch(void* const* d_in, const int* in_sizes, int n_in,
                              void* d_out, int out_size, void* d_ws, size_t ws_size,
                              hipStream_t stream) {
    const float* pred = (const float*)d_in[0];
    char* ws = (char*)d_ws;
    float*  det     = (float*) (ws + OFF_DET);
    float4* boxes   = (float4*)(ws + OFF_BOXES);
    u64*    keys    = (u64*)   (ws + OFF_KEYS);
    int*    sidx    = (int*)   (ws + OFF_SIDX);
    float*  det_s   = (float*) (ws + OFF_DETS);
    float4* boxes_s = (float4*)(ws + OFF_BOXESS);
    u64*    mask    = (u64*)   (ws + OFF_MASK);
    u64*    keepw   = (u64*)   (ws + OFF_KEEPW);
    int*    vcount  = (int*)   (ws + OFF_VCNT);

    hipMemsetAsync(vcount, 0, 4, stream);
    prep_k  <<<(N_BOX + 255) / 256, 256, 0, stream>>>(pred, det, boxes, keys, vcount);
    rank_k  <<<(N_BOX + 255) / 256, 256, 0, stream>>>(keys, sidx);
    gather_k<<<(N_BOX + 255) / 256, 256, 0, stream>>>(sidx, (const float4*)det, boxes,
                                                      (float4*)det_s, boxes_s);
    mask_k  <<<dim3(NW, NW), 64, 0, stream>>>(boxes_s, mask);
    scan_k  <<<1, 64, 0, stream>>>(mask, vcount, keepw);
    out_k   <<<(N_BOX * 7 + 255) / 256, 256, 0, stream>>>(det_s, keepw, (float*)d_out);
}

// Round 6
// 179.711 us; speedup vs baseline: 15.5230x; 1.4396x over previous
//
#include <hip/hip_runtime.h>
#include <stdint.h>

#define N_BOX 8400
#define NCLS 80
#define PSTRIDE 85
#define NW 132            // 64-bit words covering 8400
#define NSB 33            // 256-box super-blocks
#define CONF_T 0.01f
#define NMS_T 0.2f

typedef unsigned long long u64;

// ws layout (bytes)
#define OFF_DET     0                    // 8400 x 8 f32   = 268800
#define OFF_KEYS    268800               // 8400 u64       = 67200
#define OFF_DETS    336000               // 8400 x 8 f32   = 268800
#define OFF_BOXESS  604800               // 8400 float4    = 134400
#define OFF_MASK    739200               // 8400 x 132 u64 = 8870400 (16B aligned)
#define OFF_KEEPW   9609600              // 132 u64        = 1056
#define OFF_VCNT    9610656              // 1 int

__device__ __forceinline__ unsigned fmap_desc(float f) {
    unsigned u = __float_as_uint(f);
    unsigned m = (u & 0x80000000u) ? ~u : (u | 0x80000000u); // monotone ascending
    return ~m;                                               // descending
}

__device__ __forceinline__ u64 readlane64(u64 v, int lane) {
    unsigned lo = (unsigned)__builtin_amdgcn_readlane((int)(unsigned)v, lane);
    unsigned hi = (unsigned)__builtin_amdgcn_readlane((int)(unsigned)(v >> 32), lane);
    return ((u64)hi << 32) | lo;
}

__device__ __forceinline__ u64 wmask(int w, int V) {
    int nb = V - (w << 6);
    if (nb <= 0) return 0ull;
    if (nb >= 64) return ~0ull;
    return (1ull << nb) - 1ull;
}

__device__ __forceinline__ int nextbit4(u64& r0, u64& r1, u64& r2, u64& r3, int prev) {
    if (r0) { int b = __builtin_ctzll(r0); r0 &= r0 - 1; return b; }
    if (r1) { int b = __builtin_ctzll(r1); r1 &= r1 - 1; return 64 + b; }
    if (r2) { int b = __builtin_ctzll(r2); r2 &= r2 - 1; return 128 + b; }
    if (r3) { int b = __builtin_ctzll(r3); r3 &= r3 - 1; return 192 + b; }
    return prev;
}

// ---- kernel A: per-row preprocess, 4 lanes per row ----
__global__ __launch_bounds__(256) void prep_k(const float* __restrict__ pred,
                                              float* __restrict__ det,
                                              u64* __restrict__ keys) {
    int gt = blockIdx.x * 256 + threadIdx.x;
    int i = gt >> 2, q = gt & 3;
    if (i >= N_BOX) return;
    const float* p = pred + (size_t)i * PSTRIDE;
    int cbase = q * 20;
    float best = p[5 + cbase];
    int arg = cbase;
    for (int c = 1; c < 20; ++c) {
        float v = p[5 + cbase + c];
        if (v > best) { best = v; arg = cbase + c; }   // strict > : first max in segment
    }
    // quad-combine: larger value wins; tie -> smaller class index (numpy first-max)
    for (int d = 1; d < 4; d <<= 1) {
        float ob = __shfl_xor(best, d);
        int   oa = __shfl_xor(arg, d);
        if (ob > best || (ob == best && oa < arg)) { best = ob; arg = oa; }
    }
    if (q == 0) {
        float cx = p[0], cy = p[1], w = p[2], h = p[3], obj = p[4];
        float hw = __fmul_rn(w, 0.5f), hh = __fmul_rn(h, 0.5f);
        float x1 = __fsub_rn(cx, hw), y1 = __fsub_rn(cy, hh);
        float x2 = __fadd_rn(cx, hw), y2 = __fadd_rn(cy, hh);
        bool valid = (obj >= CONF_T);
        float score = valid ? obj : -1.0f;
        keys[i] = ((u64)fmap_desc(score) << 32) | (unsigned)i;
        float4* dr = (float4*)(det + (size_t)i * 8);
        dr[0] = make_float4(x1, y1, x2, y2);
        dr[1] = make_float4(obj, best, (float)arg, 0.0f);
    }
}

// ---- kernel B: rank + scatter. 32 keys/block, 8 j-slices, LDS reduce. ----
// Also computes V (valid count) — valid key <=> top bit clear (score >= 0 mapped).
__global__ __launch_bounds__(256) void rank_k(const u64* __restrict__ keys,
                                              const float* __restrict__ det,
                                              float4* __restrict__ det_s,
                                              float4* __restrict__ boxes_s,
                                              int* __restrict__ vcount) {
    int t = threadIdx.x;
    int i = blockIdx.x * 32 + (t & 31);
    int s = t >> 5;                    // slice 0..7, 1050 keys each
    u64 my = (i < N_BOX) ? keys[i] : ~0ull;
    int cnt = 0, cv = 0;
    int j0 = s * 1050, j1 = j0 + 1050;
    for (int j = j0; j < j1; j += 2) {
        ulonglong2 kk = *(const ulonglong2*)(keys + j);
        cnt += (kk.x < my) + (kk.y < my);
        cv  += ((long long)kk.x >= 0) + ((long long)kk.y >= 0);
    }
    __shared__ int sc[256], sv[256];
    sc[t] = cnt; sv[t] = cv;
    __syncthreads();
    if (t < 32) {
        int r = sc[t] + sc[t + 32] + sc[t + 64] + sc[t + 96]
              + sc[t + 128] + sc[t + 160] + sc[t + 192] + sc[t + 224];
        if (i < N_BOX) {
            const float4* dr = (const float4*)(det + (size_t)i * 8);
            float4 b0 = dr[0], b1 = dr[1];
            det_s[(size_t)r * 2]     = b0;
            det_s[(size_t)r * 2 + 1] = b1;
            boxes_s[r] = b0;
        }
        if (blockIdx.x == 0 && t == 0) {
            *vcount = sv[0] + sv[32] + sv[64] + sv[96]
                    + sv[128] + sv[160] + sv[192] + sv[224];
        }
    }
}

// ---- kernel C: suppression bitmask, UPPER TRIANGLE ONLY (no zero-fill). ----
// Lower-triangle words stay poisoned; scan only ever consumes upper-tri words.
__global__ __launch_bounds__(64) void mask_k(const float4* __restrict__ boxes_s,
                                             u64* __restrict__ mask) {
    int tt = blockIdx.x, lane = threadIdx.x;
    // decode linear t -> (rb, cb), rb<=cb ; f(rb) = rb*NW - rb*(rb-1)/2
    int rb = (int)((2.0f * NW + 1.0f
                    - sqrtf((2.0f * NW + 1.0f) * (2.0f * NW + 1.0f) - 8.0f * (float)tt)) * 0.5f);
    while (rb > 0 && rb * NW - rb * (rb - 1) / 2 > tt) rb--;
    while ((rb + 1) * NW - (rb + 1) * rb / 2 <= tt) rb++;
    int cb = rb + (tt - (rb * NW - rb * (rb - 1) / 2));

    __shared__ float4 cB[64];
    __shared__ float  cA[64];
    int c0 = cb * 64 + lane;
    float4 b = (c0 < N_BOX) ? boxes_s[c0] : make_float4(0.f, 0.f, 0.f, 0.f);
    cB[lane] = b;
    cA[lane] = __fmul_rn(__fsub_rn(b.z, b.x), __fsub_rn(b.w, b.y));
    __syncthreads();
    int r = rb * 64 + lane;
    if (r >= N_BOX) return;
    float4 rx = boxes_s[r];
    float ra = __fmul_rn(__fsub_rn(rx.z, rx.x), __fsub_rn(rx.w, rx.y));
    u64 bits = 0ull;
    int cbase = cb * 64;
    for (int j = 0; j < 64; ++j) {
        int c = cbase + j;
        if (c >= N_BOX || c <= r) continue;
        float4 cx4 = cB[j];
        float ltx = fmaxf(rx.x, cx4.x), lty = fmaxf(rx.y, cx4.y);
        float rbx = fminf(rx.z, cx4.z), rby = fminf(rx.w, cx4.w);
        float wx = fmaxf(__fsub_rn(rbx, ltx), 0.0f);
        float wy = fmaxf(__fsub_rn(rby, lty), 0.0f);
        float inter = __fmul_rn(wx, wy);
        float denom = __fadd_rn(__fsub_rn(__fadd_rn(ra, cA[j]), inter), 1e-9f);
        float iou = __fdiv_rn(inter, denom);
        if (iou > NMS_T) bits |= (1ull << j);
    }
    mask[(size_t)r * NW + cb] = bits;
}

// ---- scan helpers ----
// diag tile for super-block W: q{g}{k} at lane l = mask[(256W+64g+l)*NW + 4W+k].
// Only k>=g is consumed (k<g is lower-triangle garbage).
__device__ __forceinline__ void load_diag(int W, int lane, const u64* __restrict__ mask,
    u64& q00, u64& q01, u64& q02, u64& q03,
    u64& q10, u64& q11, u64& q12, u64& q13,
    u64& q20, u64& q21, u64& q22, u64& q23,
    u64& q30, u64& q31, u64& q32, u64& q33) {
    int Wc = W < NSB ? W : (NSB - 1);
    const u64* bp = mask + (size_t)(4 * Wc);
    int rb = 256 * Wc + lane;
    int r0 = rb;       r0 = r0 < N_BOX ? r0 : N_BOX - 1;
    int r1 = rb + 64;  r1 = r1 < N_BOX ? r1 : N_BOX - 1;
    int r2 = rb + 128; r2 = r2 < N_BOX ? r2 : N_BOX - 1;
    int r3 = rb + 192; r3 = r3 < N_BOX ? r3 : N_BOX - 1;
    ulonglong2 a, c;
    a = *(const ulonglong2*)(bp + (size_t)r0 * NW);
    c = *(const ulonglong2*)(bp + (size_t)r0 * NW + 2);
    q00 = a.x; q01 = a.y; q02 = c.x; q03 = c.y;
    a = *(const ulonglong2*)(bp + (size_t)r1 * NW);
    c = *(const ulonglong2*)(bp + (size_t)r1 * NW + 2);
    q10 = a.x; q11 = a.y; q12 = c.x; q13 = c.y;
    a = *(const ulonglong2*)(bp + (size_t)r2 * NW);
    c = *(const ulonglong2*)(bp + (size_t)r2 * NW + 2);
    q20 = a.x; q21 = a.y; q22 = c.x; q23 = c.y;
    a = *(const ulonglong2*)(bp + (size_t)r3 * NW);
    c = *(const ulonglong2*)(bp + (size_t)r3 * NW + 2);
    q30 = a.x; q31 = a.y; q32 = c.x; q33 = c.y;
}

__device__ __forceinline__ void proc_sb(int W, int V, int lane,
    const u64* __restrict__ mask, u64* __restrict__ keepw,
    u64& Ra, u64& Rb, u64& Rc,
    u64 q00, u64 q01, u64 q02, u64 q03,
    u64 q10, u64 q11, u64 q12, u64 q13,
    u64 q20, u64 q21, u64 q22, u64 q23,
    u64 q30, u64 q31, u64 q32, u64 q33) {
    int wb = 4 * W;
    auto getremv = [&](int w) -> u64 {
        u64 rw = (w < 128) ? ((w & 1) ? Rb : Ra) : Rc;
        int sl = (w < 128) ? (w >> 1) : (w - 128);
        return readlane64(rw, sl);
    };
    u64 c0 = getremv(wb + 0), c1 = getremv(wb + 1);
    u64 c2 = getremv(wb + 2), c3 = getremv(wb + 3);
    u64 m0 = wmask(wb + 0, V), m1 = wmask(wb + 1, V);
    u64 m2 = wmask(wb + 2, V), m3 = wmask(wb + 3, V);
    u64 ns;
    ns = ~c0 & m0;                           // leaders in word 0 (group 0)
    while (ns) {
        int b = __builtin_ctzll(ns); ns &= ns - 1;
        u64 w0 = readlane64(q00, b), w1 = readlane64(q01, b);
        u64 w2 = readlane64(q02, b), w3 = readlane64(q03, b);
        c0 |= w0; c1 |= w1; c2 |= w2; c3 |= w3;
        ns &= ~w0;
    }
    ns = ~c1 & m1;                           // group 1: words 1..3 valid
    while (ns) {
        int b = __builtin_ctzll(ns); ns &= ns - 1;
        u64 w1 = readlane64(q11, b), w2 = readlane64(q12, b), w3 = readlane64(q13, b);
        c1 |= w1; c2 |= w2; c3 |= w3;
        ns &= ~w1;
    }
    ns = ~c2 & m2;                           // group 2: words 2..3 valid
    while (ns) {
        int b = __builtin_ctzll(ns); ns &= ns - 1;
        u64 w2 = readlane64(q22, b), w3 = readlane64(q23, b);
        c2 |= w2; c3 |= w3;
        ns &= ~w2;
    }
    ns = ~c3 & m3;                           // group 3: word 3 valid
    while (ns) {
        int b = __builtin_ctzll(ns); ns &= ns - 1;
        u64 w3 = readlane64(q33, b);
        c3 |= w3;
        ns &= ~w3;
    }
    u64 a0 = ~c0 & m0, a1 = ~c1 & m1, a2 = ~c2 & m2, a3 = ~c3 & m3;
    if (lane == 0) {
        keepw[wb + 0] = a0; keepw[wb + 1] = a1;
        keepw[wb + 2] = a2; keepw[wb + 3] = a3;
    }
    // batch-OR alive rows, 16 rows per wait (48 loads in flight).
    int rbase = 256 * W;
    int tw = (lane < 4) ? (128 + lane) : 131;
    while (a0 | a1 | a2 | a3) {
        int g0  = nextbit4(a0, a1, a2, a3, 0);
        int g1  = nextbit4(a0, a1, a2, a3, g0);
        int g2  = nextbit4(a0, a1, a2, a3, g1);
        int g3  = nextbit4(a0, a1, a2, a3, g2);
        int g4  = nextbit4(a0, a1, a2, a3, g3);
        int g5  = nextbit4(a0, a1, a2, a3, g4);
        int g6  = nextbit4(a0, a1, a2, a3, g5);
        int g7  = nextbit4(a0, a1, a2, a3, g6);
        int g8  = nextbit4(a0, a1, a2, a3, g7);
        int g9  = nextbit4(a0, a1, a2, a3, g8);
        int g10 = nextbit4(a0, a1, a2, a3, g9);
        int g11 = nextbit4(a0, a1, a2, a3, g10);
        int g12 = nextbit4(a0, a1, a2, a3, g11);
        int g13 = nextbit4(a0, a1, a2, a3, g12);
        int g14 = nextbit4(a0, a1, a2, a3, g13);
        int g15 = nextbit4(a0, a1, a2, a3, g14);
        u64 A0,B0,T0, A1,B1,T1, A2,B2,T2, A3,B3,T3;
        u64 A4,B4,T4, A5,B5,T5, A6,B6,T6, A7,B7,T7;
        u64 A8,B8,T8, A9,B9,T9, A10,B10,T10, A11,B11,T11;
        u64 A12,B12,T12, A13,B13,T13, A14,B14,T14, A15,B15,T15;
#define ROWL(s, g) do {                                                  \
        const u64* rp_ = mask + (size_t)(rbase + (g)) * NW;              \
        ulonglong2 v_ = *(const ulonglong2*)(rp_ + 2 * lane);            \
        A##s = v_.x; B##s = v_.y; T##s = rp_[tw];                        \
    } while (0)
        ROWL(0, g0);   ROWL(1, g1);   ROWL(2, g2);   ROWL(3, g3);
        ROWL(4, g4);   ROWL(5, g5);   ROWL(6, g6);   ROWL(7, g7);
        ROWL(8, g8);   ROWL(9, g9);   ROWL(10, g10); ROWL(11, g11);
        ROWL(12, g12); ROWL(13, g13); ROWL(14, g14); ROWL(15, g15);
#undef ROWL
        Ra |= ((A0|A1)|(A2|A3)) | ((A4|A5)|(A6|A7))
            | ((A8|A9)|(A10|A11)) | ((A12|A13)|(A14|A15));
        Rb |= ((B0|B1)|(B2|B3)) | ((B4|B5)|(B6|B7))
            | ((B8|B9)|(B10|B11)) | ((B12|B13)|(B14|B15));
        Rc |= ((T0|T1)|(T2|T3)) | ((T4|T5)|(T6|T7))
            | ((T8|T9)|(T10|T11)) | ((T12|T13)|(T14|T15));
    }
}

// ---- kernel D: block-wise greedy scan over 256-box super-blocks, one wave ----
__global__ __launch_bounds__(64) void scan_k(const u64* __restrict__ mask,
                                             const int* __restrict__ vcount,
                                             u64* __restrict__ keepw) {
    int lane = threadIdx.x;
    int V = *vcount;
    u64 Ra = 0ull, Rb = 0ull, Rc = 0ull;
    u64 q00,q01,q02,q03,q10,q11,q12,q13,q20,q21,q22,q23,q30,q31,q32,q33;
    u64 n00,n01,n02,n03,n10,n11,n12,n13,n20,n21,n22,n23,n30,n31,n32,n33;

#define LQ(P, W) load_diag((W), lane, mask, P##00,P##01,P##02,P##03, P##10,P##11,P##12,P##13, \
                           P##20,P##21,P##22,P##23, P##30,P##31,P##32,P##33)
#define PS(P, W) proc_sb((W), V, lane, mask, keepw, Ra, Rb, Rc,          \
                         P##00,P##01,P##02,P##03, P##10,P##11,P##12,P##13, \
                         P##20,P##21,P##22,P##23, P##30,P##31,P##32,P##33)
    LQ(q, 0);
    int W = 0;
    for (; W + 1 < NSB; W += 2) {
        LQ(n, W + 1);
        PS(q, W);
        LQ(q, W + 2);
        PS(n, W + 1);
    }
    PS(q, W);            // W == 32 (NSB odd)
#undef LQ
#undef PS
}

// ---- kernel E: masked write-out (7 cols) ----
__global__ __launch_bounds__(256) void out_k(const float* __restrict__ det_s,
                                             const u64* __restrict__ keepw,
                                             float* __restrict__ out) {
    int e = blockIdx.x * 256 + threadIdx.x;
    if (e >= N_BOX * 7) return;
    int r = e / 7, c = e - r * 7;
    bool k = (keepw[r >> 6] >> (r & 63)) & 1ull;
    out[e] = k ? det_s[r * 8 + c] : 0.0f;
}

extern "C" void kernel_launch(void* const* d_in, const int* in_sizes, int n_in,
                              void* d_out, int out_size, void* d_ws, size_t ws_size,
                              hipStream_t stream) {
    const float* pred = (const float*)d_in[0];
    char* ws = (char*)d_ws;
    float*  det     = (float*) (ws + OFF_DET);
    u64*    keys    = (u64*)   (ws + OFF_KEYS);
    float*  det_s   = (float*) (ws + OFF_DETS);
    float4* boxes_s = (float4*)(ws + OFF_BOXESS);
    u64*    mask    = (u64*)   (ws + OFF_MASK);
    u64*    keepw   = (u64*)   (ws + OFF_KEEPW);
    int*    vcount  = (int*)   (ws + OFF_VCNT);

    prep_k<<<132, 256, 0, stream>>>(pred, det, keys);
    rank_k<<<264, 256, 0, stream>>>(keys, det, (float4*)det_s, boxes_s, vcount);
    mask_k<<<NW * (NW + 1) / 2, 64, 0, stream>>>(boxes_s, mask);
    scan_k<<<1, 64, 0, stream>>>(mask, vcount, keepw);
    out_k <<<(N_BOX * 7 + 255) / 256, 256, 0, stream>>>(det_s, keepw, (float*)d_out);
}